// Round 1
// baseline (6009.754 us; speedup 1.0000x reference)
//
#include <hip/hip_runtime.h>
#include <cstdint>
#include <cstddef>

#define NN 100000
#define NE 1600000
#define DIN 128
#define DE 64
#define HID 128
#define NC 20
#define NEG 0.2f

// ---------------- ve = We @ att_e (fold he@att_e into edge_attr @ ve) -------
__global__ void ve_kernel(const float* __restrict__ We1, const float* __restrict__ attE1,
                          const float* __restrict__ We2, const float* __restrict__ attE2,
                          float* __restrict__ ve1, float* __restrict__ ve2) {
    int j = threadIdx.x;  // 128 threads
    if (j < 64) {
        float s = 0.f;
        for (int k = 0; k < HID; k++) s += We1[j * HID + k] * attE1[k];
        ve1[j] = s;
    } else {
        int jj = j - 64;
        float s = 0.f;
        for (int k = 0; k < HID; k++) s += We2[jj * HID + k] * attE2[k];
        ve2[jj] = s;
    }
}

// ---------------- CSR build: histogram -> scan -> scatter -------------------
__global__ void hist_kernel(const int* __restrict__ ei, int* __restrict__ cnt) {
    int e = blockIdx.x * blockDim.x + threadIdx.x;
    if (e < NE) atomicAdd(&cnt[ei[NE + e]], 1);
}

__global__ void scan1_kernel(const int* __restrict__ cnt, int* __restrict__ tmp,
                             int* __restrict__ bsum) {
    __shared__ int lds[1024];
    int t = threadIdx.x;
    int i = blockIdx.x * 1024 + t;
    int v = (i < NN) ? cnt[i] : 0;
    lds[t] = v;
    __syncthreads();
    for (int off = 1; off < 1024; off <<= 1) {
        int o = (t >= off) ? lds[t - off] : 0;
        __syncthreads();
        lds[t] += o;
        __syncthreads();
    }
    if (i < NN) tmp[i] = lds[t];
    if (t == 1023) bsum[blockIdx.x] = lds[1023];
}

__global__ void scan2_kernel(const int* __restrict__ bsum, int* __restrict__ boff, int nb) {
    if (threadIdx.x == 0) {
        int r = 0;
        for (int b = 0; b < nb; b++) { boff[b] = r; r += bsum[b]; }
    }
}

__global__ void scan3_kernel(const int* __restrict__ tmp, const int* __restrict__ boff,
                             int* __restrict__ rowptr) {
    int i = blockIdx.x * blockDim.x + threadIdx.x;
    if (i < NN) rowptr[i + 1] = tmp[i] + boff[i >> 10];
    if (i == 0) rowptr[0] = 0;
}

// ---------------- a_edge for BOTH layers in one edge_attr pass --------------
__global__ __launch_bounds__(256) void aedge_kernel(const float* __restrict__ ea,
                                                    const float* __restrict__ ve1,
                                                    const float* __restrict__ ve2,
                                                    float* __restrict__ aeo1,
                                                    float* __restrict__ aeo2) {
    __shared__ float v1[64], v2[64];
    int t = threadIdx.x;
    if (t < 64) v1[t] = ve1[t];
    else if (t < 128) v2[t - 64] = ve2[t - 64];
    __syncthreads();
    int e = blockIdx.x * blockDim.x + t;
    if (e >= NE) return;
    const float4* r = (const float4*)(ea + (size_t)e * DE);
    float a1 = 0.f, a2 = 0.f;
#pragma unroll
    for (int i = 0; i < 16; i++) {
        float4 v = r[i];
        a1 += v.x * v1[4 * i] + v.y * v1[4 * i + 1] + v.z * v1[4 * i + 2] + v.w * v1[4 * i + 3];
        a2 += v.x * v2[4 * i] + v.y * v2[4 * i + 1] + v.z * v2[4 * i + 2] + v.w * v2[4 * i + 3];
    }
    aeo1[e] = a1;
    aeo2[e] = a2;
}

__global__ void scatter_kernel(const int* __restrict__ ei, const int* __restrict__ rowptr,
                               int* __restrict__ fill, const float* __restrict__ ae1,
                               const float* __restrict__ ae2, int* __restrict__ esrc,
                               float* __restrict__ ae1s, float* __restrict__ ae2s) {
    int e = blockIdx.x * blockDim.x + threadIdx.x;
    if (e >= NE) return;
    int s = ei[e];
    int d = ei[NE + e];
    int p = rowptr[d] + atomicAdd(&fill[d], 1);
    esrc[p] = s;
    ae1s[p] = ae1[e];
    ae2s[p] = ae2[e];
}

// ---------------- g = x @ W, fused a_s = g.att_s, a_d = g.att_d -------------
__global__ __launch_bounds__(256) void gemm_att_kernel(const float* __restrict__ x,
                                                       const float* __restrict__ W,
                                                       const float* __restrict__ atts,
                                                       const float* __restrict__ attd,
                                                       float* __restrict__ g,
                                                       float* __restrict__ a_s,
                                                       float* __restrict__ a_d, int nwaves) {
    __shared__ float Wl[128 * 128];
    int t = threadIdx.x;
    const float4* W4 = (const float4*)W;
    float4* Wl4 = (float4*)Wl;
    for (int i = t; i < 4096; i += 256) Wl4[i] = W4[i];
    __syncthreads();
    int lane = t & 63, wid = t >> 6;
    int gw = blockIdx.x * 4 + wid;
    float s0 = atts[lane], s1 = atts[lane + 64];
    float d0 = attd[lane], d1 = attd[lane + 64];
    for (int r0 = gw * 4; r0 < NN; r0 += nwaves * 4) {
        float acc[4][2] = {};
        const float4* xr[4];
#pragma unroll
        for (int j = 0; j < 4; j++) {
            int row = r0 + j;
            if (row >= NN) row = NN - 1;  // dummy, store guarded
            xr[j] = (const float4*)(x + (size_t)row * 128);
        }
        for (int k4 = 0; k4 < 32; k4++) {
            float4 xv[4];
#pragma unroll
            for (int j = 0; j < 4; j++) xv[j] = xr[j][k4];
#pragma unroll
            for (int kk = 0; kk < 4; kk++) {
                float w0 = Wl[(k4 * 4 + kk) * 128 + lane];
                float w1 = Wl[(k4 * 4 + kk) * 128 + lane + 64];
#pragma unroll
                for (int j = 0; j < 4; j++) {
                    float xs = ((const float*)&xv[j])[kk];
                    acc[j][0] = fmaf(xs, w0, acc[j][0]);
                    acc[j][1] = fmaf(xs, w1, acc[j][1]);
                }
            }
        }
#pragma unroll
        for (int j = 0; j < 4; j++) {
            int row = r0 + j;
            if (row >= NN) break;
            g[(size_t)row * 128 + lane] = acc[j][0];
            g[(size_t)row * 128 + lane + 64] = acc[j][1];
            float as = acc[j][0] * s0 + acc[j][1] * s1;
            float ad = acc[j][0] * d0 + acc[j][1] * d1;
#pragma unroll
            for (int off = 32; off; off >>= 1) {
                as += __shfl_xor(as, off);
                ad += __shfl_xor(ad, off);
            }
            if (lane == 0) { a_s[row] = as; a_d[row] = ad; }
        }
    }
}

// ---------------- per-node online-softmax aggregation (1 wave / node) -------
__global__ __launch_bounds__(256) void agg_kernel(const float* __restrict__ g,
                                                  const float* __restrict__ a_s,
                                                  const float* __restrict__ a_d,
                                                  const float* __restrict__ aes,
                                                  const int* __restrict__ esrc,
                                                  const int* __restrict__ rowptr,
                                                  const float* __restrict__ bias,
                                                  float* __restrict__ out, int nwaves) {
    int t = threadIdx.x;
    int lane = t & 63, wid = t >> 6;
    int gw = blockIdx.x * 4 + wid;
    int c = lane * 2;
    for (int n = gw; n < NN; n += nwaves) {
        int p0 = rowptr[n], p1 = rowptr[n + 1];
        float adn = a_d[n];
        float m = -1e30f, ssum = 0.f, A0 = 0.f, A1 = 0.f;
        for (int p = p0; p < p1; p++) {
            int s = esrc[p];
            float al = a_s[s] + adn + aes[p];
            al = (al > 0.f) ? al : NEG * al;
            float nm = fmaxf(m, al);
            float sc = __expf(m - nm);
            float pr = __expf(al - nm);
            float2 gv = *(const float2*)(g + (size_t)s * 128 + c);
            ssum = ssum * sc + pr;
            A0 = A0 * sc + pr * gv.x;
            A1 = A1 * sc + pr * gv.y;
            m = nm;
        }
        float rden = (ssum > 0.f) ? 1.f / ssum : 0.f;
        out[(size_t)n * 128 + c] = A0 * rden + bias[c];
        out[(size_t)n * 128 + c + 1] = A1 * rden + bias[c + 1];
    }
}

// ---------------- classifier: logits = h2@Wl + bl, row softmax --------------
__global__ __launch_bounds__(256) void cls_kernel(const float* __restrict__ h,
                                                  const float* __restrict__ Wlm,
                                                  const float* __restrict__ bl,
                                                  float* __restrict__ out) {
    __shared__ float wl[128 * NC];
    __shared__ float bls[NC];
    int t = threadIdx.x;
    for (int i = t; i < 128 * NC; i += 256) wl[i] = Wlm[i];
    if (t < NC) bls[t] = bl[t];
    __syncthreads();
    int n = blockIdx.x * 256 + t;
    if (n >= NN) return;
    float acc[NC];
#pragma unroll
    for (int cc = 0; cc < NC; cc++) acc[cc] = bls[cc];
    const float4* hr = (const float4*)(h + (size_t)n * 128);
    for (int k4 = 0; k4 < 32; k4++) {
        float4 v = hr[k4];
#pragma unroll
        for (int kk = 0; kk < 4; kk++) {
            float xv = ((const float*)&v)[kk];
#pragma unroll
            for (int cc = 0; cc < NC; cc++) acc[cc] = fmaf(xv, wl[(k4 * 4 + kk) * NC + cc], acc[cc]);
        }
    }
    float mx = acc[0];
#pragma unroll
    for (int cc = 1; cc < NC; cc++) mx = fmaxf(mx, acc[cc]);
    float s = 0.f;
#pragma unroll
    for (int cc = 0; cc < NC; cc++) { acc[cc] = __expf(acc[cc] - mx); s += acc[cc]; }
    float r = 1.f / s;
#pragma unroll
    for (int cc = 0; cc < NC; cc++) out[(size_t)n * NC + cc] = acc[cc] * r;
}

// ---------------------------------------------------------------------------
extern "C" void kernel_launch(void* const* d_in, const int* in_sizes, int n_in,
                              void* d_out, int out_size, void* d_ws, size_t ws_size,
                              hipStream_t stream) {
    const float* x    = (const float*)d_in[0];
    const int*   ei   = (const int*)d_in[1];      // [2,E] int32
    const float* ea   = (const float*)d_in[2];
    const float* W1   = (const float*)d_in[3];
    const float* as1  = (const float*)d_in[4];
    const float* ad1  = (const float*)d_in[5];
    const float* We1  = (const float*)d_in[6];
    const float* aE1  = (const float*)d_in[7];
    const float* b1   = (const float*)d_in[8];
    const float* W2   = (const float*)d_in[9];
    const float* as2  = (const float*)d_in[10];
    const float* ad2  = (const float*)d_in[11];
    const float* We2  = (const float*)d_in[12];
    const float* aE2  = (const float*)d_in[13];
    const float* b2   = (const float*)d_in[14];
    const float* Wl   = (const float*)d_in[15];
    const float* bl   = (const float*)d_in[16];

    char* ws = (char*)d_ws;
    size_t off = 0;
    auto alloc = [&](size_t bytes) -> void* {
        void* p = ws + off;
        off = (off + bytes + 255) & ~(size_t)255;
        return p;
    };
    float* bufG  = (float*)alloc((size_t)NN * 128 * 4);
    float* bufH  = (float*)alloc((size_t)NN * 128 * 4);
    float* aS    = (float*)alloc((size_t)NN * 4);
    float* aD    = (float*)alloc((size_t)NN * 4);
    float* ae1   = (float*)alloc((size_t)NE * 4);
    float* ae2   = (float*)alloc((size_t)NE * 4);
    float* ae1s  = (float*)alloc((size_t)NE * 4);
    float* ae2s  = (float*)alloc((size_t)NE * 4);
    int*   esrc  = (int*)alloc((size_t)NE * 4);
    int*   cnt   = (int*)alloc((size_t)NN * 4);
    int*   tmp   = (int*)alloc((size_t)NN * 4);
    int*   rowptr= (int*)alloc((size_t)(NN + 1) * 4);
    int*   fill  = (int*)alloc((size_t)NN * 4);
    int*   bsum  = (int*)alloc(512);
    int*   boff  = (int*)alloc(512);
    float* ve1   = (float*)alloc(256);
    float* ve2   = (float*)alloc(256);

    hipMemsetAsync(cnt, 0, (size_t)NN * 4, stream);
    hipMemsetAsync(fill, 0, (size_t)NN * 4, stream);

    const int NB_SCAN = (NN + 1023) / 1024;  // 98

    ve_kernel<<<1, 128, 0, stream>>>(We1, aE1, We2, aE2, ve1, ve2);
    hist_kernel<<<(NE + 255) / 256, 256, 0, stream>>>(ei, cnt);
    scan1_kernel<<<NB_SCAN, 1024, 0, stream>>>(cnt, tmp, bsum);
    scan2_kernel<<<1, 64, 0, stream>>>(bsum, boff, NB_SCAN);
    scan3_kernel<<<(NN + 255) / 256, 256, 0, stream>>>(tmp, boff, rowptr);
    aedge_kernel<<<(NE + 255) / 256, 256, 0, stream>>>(ea, ve1, ve2, ae1, ae2);
    scatter_kernel<<<(NE + 255) / 256, 256, 0, stream>>>(ei, rowptr, fill, ae1, ae2,
                                                         esrc, ae1s, ae2s);

    const int NB = 2048;          // 2048 blocks * 4 waves = 8192 waves, grid-stride
    const int NW = NB * 4;
    // layer 1
    gemm_att_kernel<<<NB, 256, 0, stream>>>(x, W1, as1, ad1, bufG, aS, aD, NW);
    agg_kernel<<<NB, 256, 0, stream>>>(bufG, aS, aD, ae1s, esrc, rowptr, b1, bufH, NW);
    // layer 2
    gemm_att_kernel<<<NB, 256, 0, stream>>>(bufH, W2, as2, ad2, bufG, aS, aD, NW);
    agg_kernel<<<NB, 256, 0, stream>>>(bufG, aS, aD, ae2s, esrc, rowptr, b2, bufH, NW);
    // classifier + softmax
    cls_kernel<<<(NN + 255) / 256, 256, 0, stream>>>(bufH, Wl, bl, (float*)d_out);
}

// Round 2
// 1290.205 us; speedup vs baseline: 4.6580x; 4.6580x over previous
//
#include <hip/hip_runtime.h>
#include <cstdint>
#include <cstddef>

#define NN 100000
#define NE 1600000
#define DIN 128
#define DE 64
#define HID 128
#define NC 20
#define NEG 0.2f

// ---------------- ve = We @ att_e (fold he@att_e into edge_attr @ ve) -------
__global__ void ve_kernel(const float* __restrict__ We1, const float* __restrict__ attE1,
                          const float* __restrict__ We2, const float* __restrict__ attE2,
                          float* __restrict__ ve1, float* __restrict__ ve2) {
    int j = threadIdx.x;  // 128 threads
    if (j < 64) {
        float s = 0.f;
        for (int k = 0; k < HID; k++) s += We1[j * HID + k] * attE1[k];
        ve1[j] = s;
    } else {
        int jj = j - 64;
        float s = 0.f;
        for (int k = 0; k < HID; k++) s += We2[jj * HID + k] * attE2[k];
        ve2[jj] = s;
    }
}

// ---------------- CSR build: histogram -> scan -> scatter -------------------
__global__ void hist_kernel(const int* __restrict__ ei, int* __restrict__ cnt) {
    int e = blockIdx.x * blockDim.x + threadIdx.x;
    if (e < NE) atomicAdd(&cnt[ei[NE + e]], 1);
}

__global__ void scan1_kernel(const int* __restrict__ cnt, int* __restrict__ tmp,
                             int* __restrict__ bsum) {
    __shared__ int lds[1024];
    int t = threadIdx.x;
    int i = blockIdx.x * 1024 + t;
    int v = (i < NN) ? cnt[i] : 0;
    lds[t] = v;
    __syncthreads();
    for (int off = 1; off < 1024; off <<= 1) {
        int o = (t >= off) ? lds[t - off] : 0;
        __syncthreads();
        lds[t] += o;
        __syncthreads();
    }
    if (i < NN) tmp[i] = lds[t];
    if (t == 1023) bsum[blockIdx.x] = lds[1023];
}

__global__ void scan2_kernel(const int* __restrict__ bsum, int* __restrict__ boff, int nb) {
    if (threadIdx.x == 0) {
        int r = 0;
        for (int b = 0; b < nb; b++) { boff[b] = r; r += bsum[b]; }
    }
}

__global__ void scan3_kernel(const int* __restrict__ tmp, const int* __restrict__ boff,
                             int* __restrict__ rowptr) {
    int i = blockIdx.x * blockDim.x + threadIdx.x;
    if (i < NN) rowptr[i + 1] = tmp[i] + boff[i >> 10];
    if (i == 0) rowptr[0] = 0;
}

// ---------------- a_edge for BOTH layers in one edge_attr pass --------------
__global__ __launch_bounds__(256) void aedge_kernel(const float* __restrict__ ea,
                                                    const float* __restrict__ ve1,
                                                    const float* __restrict__ ve2,
                                                    float* __restrict__ aeo1,
                                                    float* __restrict__ aeo2) {
    __shared__ float v1[64], v2[64];
    int t = threadIdx.x;
    if (t < 64) v1[t] = ve1[t];
    else if (t < 128) v2[t - 64] = ve2[t - 64];
    __syncthreads();
    int e = blockIdx.x * blockDim.x + t;
    if (e >= NE) return;
    const float4* r = (const float4*)(ea + (size_t)e * DE);
    float a1 = 0.f, a2 = 0.f;
#pragma unroll
    for (int i = 0; i < 16; i++) {
        float4 v = r[i];
        a1 += v.x * v1[4 * i] + v.y * v1[4 * i + 1] + v.z * v1[4 * i + 2] + v.w * v1[4 * i + 3];
        a2 += v.x * v2[4 * i] + v.y * v2[4 * i + 1] + v.z * v2[4 * i + 2] + v.w * v2[4 * i + 3];
    }
    aeo1[e] = a1;
    aeo2[e] = a2;
}

__global__ void scatter_kernel(const int* __restrict__ ei, const int* __restrict__ rowptr,
                               int* __restrict__ fill, const float* __restrict__ ae1,
                               const float* __restrict__ ae2, int* __restrict__ esrc,
                               float* __restrict__ ae1s, float* __restrict__ ae2s) {
    int e = blockIdx.x * blockDim.x + threadIdx.x;
    if (e >= NE) return;
    int s = ei[e];
    int d = ei[NE + e];
    int p = rowptr[d] + atomicAdd(&fill[d], 1);
    esrc[p] = s;
    ae1s[p] = ae1[e];
    ae2s[p] = ae2[e];
}

// ---------------- 128x128-tile SGEMM: g = x @ W, fused a_s, a_d -------------
// LDS: Xs[128][132] (padded) + Ws[128][128] + atts/attd copies = 134144 B.
// 1 block/CU; per-thread 8x8 register tile (LDS BW = 128 B/cyc matches FMA).
__global__ __launch_bounds__(256, 1) void gemm128_kernel(const float* __restrict__ x,
                                                         const float* __restrict__ W,
                                                         const float* __restrict__ atts,
                                                         const float* __restrict__ attd,
                                                         float* __restrict__ g,
                                                         float* __restrict__ a_s,
                                                         float* __restrict__ a_d) {
    extern __shared__ float lds[];
    float* Xs = lds;                      // [128][132]
    float* Ws = lds + 128 * 132;          // [128][128]
    float* atL = Ws + 128 * 128;          // [128]
    float* adL = atL + 128;               // [128]
    int t = threadIdx.x;
    int tile0 = blockIdx.x * 128;

    if (t < 128) atL[t] = atts[t];
    else adL[t - 128] = attd[t - 128];

    // stage W (straight row-major copy, coalesced)
    const float4* W4 = (const float4*)W;
    for (int i = t; i < 4096; i += 256) {
        float4 v = W4[i];
        *(float4*)&Ws[i * 4] = v;
    }
    // stage x tile (coalesced float4, padded rows)
    for (int i = 0; i < 16; i++) {
        int flat = t + 256 * i;
        int row = flat >> 5, k4 = flat & 31;
        int rowg = tile0 + row;
        if (rowg >= NN) rowg = NN - 1;
        float4 v = *(const float4*)(x + (size_t)rowg * 128 + k4 * 4);
        *(float4*)&Xs[row * 132 + k4 * 4] = v;
    }
    __syncthreads();

    int lane = t & 63, w = t >> 6;
    int rg = w * 4 + (lane >> 4);  // 0..15, interleaved rows rg+16r
    int cg = lane & 15;            // 0..15, blocked cols cg*8..cg*8+7
    float acc[8][8] = {};

    for (int k0 = 0; k0 < 128; k0 += 4) {
        float4 xv[8];
#pragma unroll
        for (int r = 0; r < 8; r++)
            xv[r] = *(const float4*)&Xs[(rg + 16 * r) * 132 + k0];
#pragma unroll
        for (int kk = 0; kk < 4; kk++) {
            float4 wa = *(const float4*)&Ws[(k0 + kk) * 128 + cg * 8];
            float4 wb = *(const float4*)&Ws[(k0 + kk) * 128 + cg * 8 + 4];
#pragma unroll
            for (int r = 0; r < 8; r++) {
                float xs = ((const float*)&xv[r])[kk];
                acc[r][0] = fmaf(xs, wa.x, acc[r][0]);
                acc[r][1] = fmaf(xs, wa.y, acc[r][1]);
                acc[r][2] = fmaf(xs, wa.z, acc[r][2]);
                acc[r][3] = fmaf(xs, wa.w, acc[r][3]);
                acc[r][4] = fmaf(xs, wb.x, acc[r][4]);
                acc[r][5] = fmaf(xs, wb.y, acc[r][5]);
                acc[r][6] = fmaf(xs, wb.z, acc[r][6]);
                acc[r][7] = fmaf(xs, wb.w, acc[r][7]);
            }
        }
    }
    __syncthreads();
    // stage acc back into Xs for coalesced writes + row reductions
#pragma unroll
    for (int r = 0; r < 8; r++)
#pragma unroll
        for (int cc = 0; cc < 8; cc++)
            Xs[(rg + 16 * r) * 132 + cg * 8 + cc] = acc[r][cc];
    __syncthreads();
    // coalesced g writes
    for (int i = 0; i < 16; i++) {
        int flat = t + 256 * i;
        int row = flat >> 5, c4 = flat & 31;
        int rowg = tile0 + row;
        if (rowg < NN)
            *(float4*)(g + (size_t)rowg * 128 + c4 * 4) = *(const float4*)&Xs[row * 132 + c4 * 4];
    }
    // a_s / a_d: 2 threads per row
    {
        int row = t >> 1, half = t & 1;
        float s = 0.f, d = 0.f;
#pragma unroll
        for (int j = 0; j < 16; j++) {
            float4 v = *(const float4*)&Xs[row * 132 + half * 64 + 4 * j];
            float4 sa = *(const float4*)&atL[half * 64 + 4 * j];
            float4 da = *(const float4*)&adL[half * 64 + 4 * j];
            s += v.x * sa.x + v.y * sa.y + v.z * sa.z + v.w * sa.w;
            d += v.x * da.x + v.y * da.y + v.z * da.z + v.w * da.w;
        }
        s += __shfl_xor(s, 1);
        d += __shfl_xor(d, 1);
        int rowg = tile0 + row;
        if ((t & 1) == 0 && rowg < NN) { a_s[rowg] = s; a_d[rowg] = d; }
    }
}

// ---------------- per-node chunked wave-parallel softmax aggregation --------
__global__ __launch_bounds__(256) void agg_kernel(const float* __restrict__ g,
                                                  const float* __restrict__ a_s,
                                                  const float* __restrict__ a_d,
                                                  const float* __restrict__ aes,
                                                  const int* __restrict__ esrc,
                                                  const int* __restrict__ rowptr,
                                                  const float* __restrict__ bias,
                                                  float* __restrict__ out, int nwaves) {
    int t = threadIdx.x;
    int lane = t & 63, wid = t >> 6;
    int gw = blockIdx.x * 4 + wid;
    int c = lane * 2;
    for (int n = gw; n < NN; n += nwaves) {
        int p0 = rowptr[n], p1 = rowptr[n + 1];
        float adn = a_d[n];
        float m = -1e30f, ssum = 0.f, A0 = 0.f, A1 = 0.f;
        for (int base = p0; base < p1; base += 64) {
            int cnt = p1 - base;
            if (cnt > 64) cnt = 64;
            bool act = lane < cnt;
            int p = base + (act ? lane : 0);
            int s = esrc[p];
            float al = a_s[s] + adn + aes[p];
            al = (al > 0.f) ? al : NEG * al;
            if (!act) al = -1e30f;
            float mx = al;
#pragma unroll
            for (int off = 32; off; off >>= 1) mx = fmaxf(mx, __shfl_xor(mx, off));
            float nm = fmaxf(m, mx);
            float pr = act ? __expf(al - nm) : 0.f;
            float sc = __expf(m - nm);
            float ps = pr;
#pragma unroll
            for (int off = 32; off; off >>= 1) ps += __shfl_xor(ps, off);
            ssum = ssum * sc + ps;
            A0 *= sc;
            A1 *= sc;
            for (int j = 0; j < cnt; j++) {
                float prj = __shfl(pr, j);
                int sj = __shfl(s, j);
                float2 gv = *(const float2*)(g + (size_t)sj * 128 + c);
                A0 = fmaf(prj, gv.x, A0);
                A1 = fmaf(prj, gv.y, A1);
            }
            m = nm;
        }
        float rden = (ssum > 0.f) ? 1.f / ssum : 0.f;
        out[(size_t)n * 128 + c] = fmaf(A0, rden, bias[c]);
        out[(size_t)n * 128 + c + 1] = fmaf(A1, rden, bias[c + 1]);
    }
}

// ---------------- classifier: logits = h2@Wl + bl, row softmax --------------
__global__ __launch_bounds__(256) void cls_kernel(const float* __restrict__ h,
                                                  const float* __restrict__ Wlm,
                                                  const float* __restrict__ bl,
                                                  float* __restrict__ out) {
    __shared__ float wl[128 * NC];
    __shared__ float bls[NC];
    int t = threadIdx.x;
    for (int i = t; i < 128 * NC; i += 256) wl[i] = Wlm[i];
    if (t < NC) bls[t] = bl[t];
    __syncthreads();
    int n = blockIdx.x * 256 + t;
    if (n >= NN) return;
    float acc[NC];
#pragma unroll
    for (int cc = 0; cc < NC; cc++) acc[cc] = bls[cc];
    const float4* hr = (const float4*)(h + (size_t)n * 128);
    for (int k4 = 0; k4 < 32; k4++) {
        float4 v = hr[k4];
#pragma unroll
        for (int kk = 0; kk < 4; kk++) {
            float xv = ((const float*)&v)[kk];
#pragma unroll
            for (int cc = 0; cc < NC; cc++) acc[cc] = fmaf(xv, wl[(k4 * 4 + kk) * NC + cc], acc[cc]);
        }
    }
    float mx = acc[0];
#pragma unroll
    for (int cc = 1; cc < NC; cc++) mx = fmaxf(mx, acc[cc]);
    float s = 0.f;
#pragma unroll
    for (int cc = 0; cc < NC; cc++) { acc[cc] = __expf(acc[cc] - mx); s += acc[cc]; }
    float r = 1.f / s;
#pragma unroll
    for (int cc = 0; cc < NC; cc++) out[(size_t)n * NC + cc] = acc[cc] * r;
}

// ---------------------------------------------------------------------------
extern "C" void kernel_launch(void* const* d_in, const int* in_sizes, int n_in,
                              void* d_out, int out_size, void* d_ws, size_t ws_size,
                              hipStream_t stream) {
    const float* x    = (const float*)d_in[0];
    const int*   ei   = (const int*)d_in[1];      // [2,E] int32
    const float* ea   = (const float*)d_in[2];
    const float* W1   = (const float*)d_in[3];
    const float* as1  = (const float*)d_in[4];
    const float* ad1  = (const float*)d_in[5];
    const float* We1  = (const float*)d_in[6];
    const float* aE1  = (const float*)d_in[7];
    const float* b1   = (const float*)d_in[8];
    const float* W2   = (const float*)d_in[9];
    const float* as2  = (const float*)d_in[10];
    const float* ad2  = (const float*)d_in[11];
    const float* We2  = (const float*)d_in[12];
    const float* aE2  = (const float*)d_in[13];
    const float* b2   = (const float*)d_in[14];
    const float* Wl   = (const float*)d_in[15];
    const float* bl   = (const float*)d_in[16];

    char* ws = (char*)d_ws;
    size_t off = 0;
    auto alloc = [&](size_t bytes) -> void* {
        void* p = ws + off;
        off = (off + bytes + 255) & ~(size_t)255;
        return p;
    };
    float* bufG  = (float*)alloc((size_t)NN * 128 * 4);
    float* bufH  = (float*)alloc((size_t)NN * 128 * 4);
    float* aS    = (float*)alloc((size_t)NN * 4);
    float* aD    = (float*)alloc((size_t)NN * 4);
    float* ae1   = (float*)alloc((size_t)NE * 4);
    float* ae2   = (float*)alloc((size_t)NE * 4);
    float* ae1s  = (float*)alloc((size_t)NE * 4);
    float* ae2s  = (float*)alloc((size_t)NE * 4);
    int*   esrc  = (int*)alloc((size_t)NE * 4);
    int*   cnt   = (int*)alloc((size_t)NN * 4);
    int*   tmp   = (int*)alloc((size_t)NN * 4);
    int*   rowptr= (int*)alloc((size_t)(NN + 1) * 4);
    int*   fill  = (int*)alloc((size_t)NN * 4);
    int*   bsum  = (int*)alloc(512);
    int*   boff  = (int*)alloc(512);
    float* ve1   = (float*)alloc(256);
    float* ve2   = (float*)alloc(256);

    hipMemsetAsync(cnt, 0, (size_t)NN * 4, stream);
    hipMemsetAsync(fill, 0, (size_t)NN * 4, stream);

    const int NB_SCAN = (NN + 1023) / 1024;  // 98

    ve_kernel<<<1, 128, 0, stream>>>(We1, aE1, We2, aE2, ve1, ve2);
    hist_kernel<<<(NE + 255) / 256, 256, 0, stream>>>(ei, cnt);
    scan1_kernel<<<NB_SCAN, 1024, 0, stream>>>(cnt, tmp, bsum);
    scan2_kernel<<<1, 64, 0, stream>>>(bsum, boff, NB_SCAN);
    scan3_kernel<<<(NN + 255) / 256, 256, 0, stream>>>(tmp, boff, rowptr);
    aedge_kernel<<<(NE + 255) / 256, 256, 0, stream>>>(ea, ve1, ve2, ae1, ae2);
    scatter_kernel<<<(NE + 255) / 256, 256, 0, stream>>>(ei, rowptr, fill, ae1, ae2,
                                                         esrc, ae1s, ae2s);

    const int GB = (NN + 127) / 128;  // 782 tiles
    const size_t SMEM = (size_t)(128 * 132 + 128 * 128 + 256) * sizeof(float);  // 134144 B
    const int NB = 2048;              // agg: 8192 waves grid-stride
    const int NW = NB * 4;
    // layer 1
    gemm128_kernel<<<GB, 256, SMEM, stream>>>(x, W1, as1, ad1, bufG, aS, aD);
    agg_kernel<<<NB, 256, 0, stream>>>(bufG, aS, aD, ae1s, esrc, rowptr, b1, bufH, NW);
    // layer 2
    gemm128_kernel<<<GB, 256, SMEM, stream>>>(bufH, W2, as2, ad2, bufG, aS, aD);
    agg_kernel<<<NB, 256, 0, stream>>>(bufG, aS, aD, ae2s, esrc, rowptr, b2, bufH, NW);
    // classifier + softmax
    cls_kernel<<<(NN + 255) / 256, 256, 0, stream>>>(bufH, Wl, bl, (float*)d_out);
}